// Round 2
// baseline (312.354 us; speedup 1.0000x reference)
//
#include <hip/hip_runtime.h>
#include <math.h>

#define BS 2
#define QLEN 64
#define KLEN 64
#define NH 8
#define DKV 64
#define INNER 512
#define VOCAB 4096
#define NCHUNK 32
#define CHUNKV 128

// ---------------- workspace layout (bytes) ----------------
// qp    : [BS][QLEN][INNER] double        @ 0         (512 KB)
// kp    : [BS][KLEN][INNER] double        @ 512 KB    (512 KB)
// dnt   : [DKV][VOCAB]      double        @ 1 MB      (2 MB)
// E     : [VOCAB][DKV]      float         @ 3 MB      (1 MB)
// qn2   : [BS][QLEN][NH]    double        @ 4 MB      (8 KB)
// kn2   : [BS][KLEN][NH]    double        @ 4 MB+8K   (8 KB)
// G     : [BS*NH][QLEN][KLEN] double      @ 4 MB+16K  (512 KB)
// bestp : [16][32][64][64]  double        @ 5 MB      (16 MB)
// idxp  : [16][32][64][64]  u16           @ 21 MB     (4 MB)
// total ~25.5 MB

// ---- tiled fp64 GEMM for q_proj/k_proj ----
// rows 0..255: rt0=(q,b0) rt1=(q,b1) rt2=(k,b0) rt3=(k,b1); 64x64 output tiles
__global__ __launch_bounds__(256) void k_proj(
    const float* __restrict__ q_in, const float* __restrict__ k_in,
    const float* __restrict__ qpe, const float* __restrict__ kpe,
    const float* __restrict__ wi,
    double* __restrict__ qp, double* __restrict__ kp)
{
    int bid = blockIdx.x;            // 32 blocks = rt(4) * ct(8)
    int rt = bid >> 3, ct = bid & 7;
    int side = rt >> 1, b = rt & 1;
    const float* xin = side ? k_in : q_in;
    const float* pin = side ? kpe : qpe;
    double* outp = side ? kp : qp;
    int wrow0 = side ? INNER : 0;

    __shared__ double As[64 * 66];   // [k][row], padded
    __shared__ double Ws[64 * 66];   // [k][col], padded
    int t = threadIdx.x;
    int ty = t >> 4, tx = t & 15;
    double acc[4][4];
    #pragma unroll
    for (int i = 0; i < 4; ++i)
        #pragma unroll
        for (int j = 0; j < 4; ++j) acc[i][j] = 0.0;

    for (int kb = 0; kb < INNER; kb += 64) {
        __syncthreads();
        for (int i = t; i < 4096; i += 256) {
            int rr = i >> 6, kk = i & 63;
            int g = (b * 64 + rr) * INNER + kb + kk;
            As[kk * 66 + rr] = (double)xin[g] + (double)pin[g];
        }
        for (int i = t; i < 4096; i += 256) {
            int kk = i >> 6, cc = i & 63;
            Ws[kk * 66 + cc] = (double)wi[(size_t)(wrow0 + kb + kk) * INNER + ct * 64 + cc];
        }
        __syncthreads();
        for (int k = 0; k < 64; ++k) {
            double a[4], w[4];
            #pragma unroll
            for (int i = 0; i < 4; ++i) a[i] = As[k * 66 + ty * 4 + i];
            #pragma unroll
            for (int j = 0; j < 4; ++j) w[j] = Ws[k * 66 + tx * 4 + j];
            #pragma unroll
            for (int i = 0; i < 4; ++i)
                #pragma unroll
                for (int j = 0; j < 4; ++j)
                    acc[i][j] = fma(a[i], w[j], acc[i][j]);
        }
    }
    #pragma unroll
    for (int i = 0; i < 4; ++i) {
        int r = ty * 4 + i;
        #pragma unroll
        for (int j = 0; j < 4; ++j)
            outp[(size_t)(b * 64 + r) * INNER + ct * 64 + tx * 4 + j] = acc[i][j];
    }
}

// per-vocab-row: l2norm (transposed store) + E = LN(row) @ vq_o_w
__global__ void k_dict(const float* __restrict__ vq, const float* __restrict__ g,
                       const float* __restrict__ bta, const float* __restrict__ ow,
                       double* __restrict__ dnt, float* __restrict__ E)
{
    int v = blockIdx.x;           // 4096 blocks, 64 threads (one wave)
    int j = threadIdx.x;
    double z = (double)vq[v * DKV + j];
    double s2 = z * z, s1 = z;
    for (int m = 32; m >= 1; m >>= 1) { s2 += __shfl_xor(s2, m); s1 += __shfl_xor(s1, m); }
    double dn = z * (1.0 / sqrt(fmax(s2, 1e-12)));
    dnt[j * VOCAB + v] = dn;
    double mean = s1 * (1.0 / 64.0);
    double d0 = z - mean;
    double vv = d0 * d0;
    for (int m = 32; m >= 1; m >>= 1) vv += __shfl_xor(vv, m);
    vv *= (1.0 / 64.0);
    double ln = d0 * (1.0 / sqrt(vv + 1e-6)) * (double)g[j] + (double)bta[j];
    __shared__ double lns[DKV];
    lns[j] = ln;
    __syncthreads();
    double acc = 0.0;
    for (int jj = 0; jj < DKV; ++jj)
        acc = fma(lns[jj], (double)ow[jj * DKV + j], acc);
    E[v * DKV + j] = (float)acc;
}

// per (b,h): qn2[q], kn2[k], Gram G[q][k] = qp_h[q] . kp_h[k]
__global__ void k_gram(const double* __restrict__ qp, const double* __restrict__ kp,
                       double* __restrict__ qn2, double* __restrict__ kn2,
                       double* __restrict__ G)
{
    int bh = blockIdx.x;            // 16 blocks
    int b = bh >> 3, h = bh & 7;
    __shared__ double qph[QLEN][DKV + 1];
    __shared__ double kph[KLEN][DKV + 1];
    int t = threadIdx.x;
    for (int idx = t; idx < QLEN * DKV; idx += 256) {
        int r = idx >> 6, j = idx & 63;
        qph[r][j] = qp[(b * QLEN + r) * INNER + h * DKV + j];
        kph[r][j] = kp[(b * KLEN + r) * INNER + h * DKV + j];
    }
    __syncthreads();
    if (t < 64) {
        double s = 0.0;
        for (int j = 0; j < DKV; ++j) s = fma(qph[t][j], qph[t][j], s);
        qn2[(b * QLEN + t) * NH + h] = s;
    } else if (t < 128) {
        int k = t - 64;
        double s = 0.0;
        for (int j = 0; j < DKV; ++j) s = fma(kph[k][j], kph[k][j], s);
        kn2[(b * KLEN + k) * NH + h] = s;
    }
    for (int p = t; p < QLEN * KLEN; p += 256) {
        int q = p >> 6, k = p & 63;
        double s = 0.0;
        for (int j = 0; j < DKV; ++j) s = fma(qph[q][j], kph[k][j], s);
        G[(size_t)(bh * QLEN + q) * KLEN + k] = s;
    }
}

// ---- FUSED sim + max-plus scan ----
// block = (bh, vchunk of 128). Computes qs/ks for its chunk entirely in LDS,
// then scans max_v(qs[q][v]+ks[k][v]) over the chunk -> per-chunk partials.
__global__ __launch_bounds__(512) void k_simscan(
    const double* __restrict__ qp, const double* __restrict__ kp,
    const double* __restrict__ dnt,
    double* __restrict__ bestp, unsigned short* __restrict__ idxp)
{
    int bid = blockIdx.x;             // 512 blocks = chunk(32) x bh(16)
    int bh = bid & 15;
    int chunk = bid >> 4;
    int b = bh >> 3, h = bh & 7;

    // S overlays: phase 1: As[64][130] (rows) + Ds[64][130] (dnt chunk)
    //             phase 2: qk_l[128 rows][129 v]
    __shared__ double S[16640];       // 133120 B
    double* As = S;                   // [k*130 + row], rows 0..63 q, 64..127 k
    double* Ds = S + 8320;            // [k*130 + v]

    int t = threadIdx.x;

    // stage A (qp/kp head slices), transposed
    for (int i = t; i < 8192; i += 512) {
        int row = i >> 6, kk = i & 63;
        double val;
        if (row < 64) val = qp[(size_t)(b * 64 + row) * INNER + h * 64 + kk];
        else          val = kp[(size_t)(b * 64 + row - 64) * INNER + h * 64 + kk];
        As[kk * 130 + row] = val;
    }
    // stage dnt chunk
    for (int i = t; i < 8192; i += 512) {
        int kk = i >> 7, vv = i & 127;
        Ds[kk * 130 + vv] = dnt[(size_t)kk * VOCAB + chunk * CHUNKV + vv];
    }
    __syncthreads();

    // sim: C[row][v] = sum_k A[row][k] * dnt[k][v], fp64, k ascending (bitwise
    // identical to the verified round-1 accumulation order)
    int ty = t >> 5;                  // 0..15 -> 8 rows each
    int tx = t & 31;                  // 0..31 -> 4 v each
    double acc[8][4];
    #pragma unroll
    for (int i = 0; i < 8; ++i)
        #pragma unroll
        for (int j = 0; j < 4; ++j) acc[i][j] = 0.0;
    for (int k = 0; k < 64; ++k) {
        double a[8], dd[4];
        #pragma unroll
        for (int i = 0; i < 8; ++i) a[i] = As[k * 130 + ty * 8 + i];
        #pragma unroll
        for (int j = 0; j < 4; ++j) dd[j] = Ds[k * 130 + tx * 4 + j];
        #pragma unroll
        for (int i = 0; i < 8; ++i)
            #pragma unroll
            for (int j = 0; j < 4; ++j)
                acc[i][j] = fma(a[i], dd[j], acc[i][j]);
    }
    __syncthreads();                  // all reads of As/Ds done

    // write C into qk_l[row][v] (overlaying S)
    #pragma unroll
    for (int i = 0; i < 8; ++i) {
        int row = ty * 8 + i;
        #pragma unroll
        for (int j = 0; j < 4; ++j)
            S[row * 129 + tx * 4 + j] = acc[i][j];
    }
    __syncthreads();

    // max-plus scan: thread tile 4q x 2k over the 128-v chunk
    int q0 = (t & 15) * 4;
    int kb2 = (t >> 4) * 2;
    double best[4][2];
    int bidx[4][2];
    #pragma unroll
    for (int i = 0; i < 4; ++i)
        #pragma unroll
        for (int j = 0; j < 2; ++j) { best[i][j] = -1e300; bidx[i][j] = 0; }

    for (int v = 0; v < CHUNKV; ++v) {
        double qv[4], kv[2];
        #pragma unroll
        for (int i = 0; i < 4; ++i) qv[i] = S[(q0 + i) * 129 + v];
        #pragma unroll
        for (int j = 0; j < 2; ++j) kv[j] = S[(64 + kb2 + j) * 129 + v];
        #pragma unroll
        for (int i = 0; i < 4; ++i)
            #pragma unroll
            for (int j = 0; j < 2; ++j) {
                double s = qv[i] + kv[j];
                if (s > best[i][j]) { best[i][j] = s; bidx[i][j] = v; }
            }
    }

    #pragma unroll
    for (int i = 0; i < 4; ++i)
        #pragma unroll
        for (int j = 0; j < 2; ++j) {
            int q = q0 + i, k = kb2 + j;
            size_t p = ((size_t)(bh * NCHUNK + chunk) * 64 + q) * 64 + k;
            bestp[p] = best[i][j];
            idxp[p] = (unsigned short)(chunk * CHUNKV + bidx[i][j]);
        }
}

// combine chunk partials + wsim + ids/scores + E-weighted mean + final LN
__global__ __launch_bounds__(256) void k_combine(
    const double* __restrict__ bestp, const unsigned short* __restrict__ idxp,
    const double* __restrict__ qn2, const double* __restrict__ kn2,
    const double* __restrict__ G, const float* __restrict__ E,
    const float* __restrict__ lng, const float* __restrict__ lnb,
    float* __restrict__ out)
{
    int bid = blockIdx.x;             // 256 = bh(16) x qgroup(16)
    int bh = bid >> 4, qg = bid & 15;
    int b = bh >> 3, h = bh & 7;
    int t = threadIdx.x;
    int w = t >> 6, lane = t & 63;
    int q = qg * 4 + w;
    int k = lane;

    double best = -1e300; int bidx = 0;
    for (int c = 0; c < NCHUNK; ++c) {
        size_t p = ((size_t)(bh * NCHUNK + c) * 64 + q) * 64 + k;
        double v = bestp[p];
        if (v > best) { best = v; bidx = (int)idxp[p]; }   // ascending c => smallest idx on ties
    }
    double n2 = qn2[(b * QLEN + q) * NH + h] + kn2[(b * KLEN + k) * NH + h]
              + 2.0 * G[((size_t)bh * QLEN + q) * KLEN + k];
    double wsim = best * (1.0 / sqrt(fmax(n2, 1e-12)));

    size_t oidx = ((size_t)(b * QLEN + q) * KLEN + k) * NH + h;
    out[65536 + oidx] = (float)bidx;          // out_ids as float32
    out[131072 + oidx] = (float)wsim;         // r3_scores

    __shared__ float ws_l[4][64];
    __shared__ int  idx_l[4][64];
    ws_l[w][k] = (float)wsim;
    idx_l[w][k] = bidx;
    __syncthreads();

    // E-weighted mean over k + layernorm over d (lane = d)
    int d = lane;
    float acc = 0.0f;
    for (int k2 = 0; k2 < 64; ++k2)
        acc += E[idx_l[w][k2] * DKV + d] * ws_l[w][k2];
    acc *= (1.0f / 64.0f);
    float mean = acc;
    for (int m = 32; m >= 1; m >>= 1) mean += __shfl_xor(mean, m);
    mean *= (1.0f / 64.0f);
    float dv = acc - mean;
    float var = dv * dv;
    for (int m = 32; m >= 1; m >>= 1) var += __shfl_xor(var, m);
    var *= (1.0f / 64.0f);
    float o = dv * rsqrtf(var + 1e-6f) * lng[d] + lnb[d];
    out[(((size_t)b * NH + h) * QLEN + q) * DKV + d] = o;
}

extern "C" void kernel_launch(void* const* d_in, const int* in_sizes, int n_in,
                              void* d_out, int out_size, void* d_ws, size_t ws_size,
                              hipStream_t stream) {
    const float* query = (const float*)d_in[0];
    const float* key   = (const float*)d_in[1];
    const float* qpe   = (const float*)d_in[2];
    const float* kpe   = (const float*)d_in[3];
    const float* wi    = (const float*)d_in[4];
    const float* vq    = (const float*)d_in[5];
    const float* vqg   = (const float*)d_in[6];
    const float* vqb   = (const float*)d_in[7];
    const float* ow    = (const float*)d_in[8];
    const float* lng   = (const float*)d_in[9];
    const float* lnb   = (const float*)d_in[10];
    float* out = (float*)d_out;

    char* ws = (char*)d_ws;
    double* qp  = (double*)(ws + 0);
    double* kp  = (double*)(ws + 524288);
    double* dnt = (double*)(ws + 1048576);
    float*  E   = (float*) (ws + 3145728);
    double* qn2 = (double*)(ws + 4194304);
    double* kn2 = (double*)(ws + 4202496);
    double* G   = (double*)(ws + 4210688);
    double* bestp = (double*)(ws + 5242880);
    unsigned short* idxp = (unsigned short*)(ws + 22020096);

    k_proj   <<<32, 256, 0, stream>>>(query, key, qpe, kpe, wi, qp, kp);
    k_dict   <<<4096, 64, 0, stream>>>(vq, vqg, vqb, ow, dnt, E);
    k_gram   <<<16, 256, 0, stream>>>(qp, kp, qn2, kn2, G);
    k_simscan<<<512, 512, 0, stream>>>(qp, kp, dnt, bestp, idxp);
    k_combine<<<256, 256, 0, stream>>>(bestp, idxp, qn2, kn2, G, E, lng, lnb, out);
}

// Round 4
// 225.045 us; speedup vs baseline: 1.3880x; 1.3880x over previous
//
#include <hip/hip_runtime.h>
#include <math.h>

#define BS 2
#define QLEN 64
#define KLEN 64
#define NH 8
#define DKV 64
#define INNER 512
#define VOCAB 4096
#define NCHUNK 32
#define CHUNKV 128
#define RS 129            // Cv stride (doubles): lane-stride 8B, conflict-free

// ---------------- workspace layout (bytes) ----------------
// qp    : [BS][64][INNER] double  @ 0        (512 KB)
// kp    : [BS][64][INNER] double  @ 512 KB   (512 KB)
// dnt   : [DKV][VOCAB]    double  @ 1 MB     (2 MB)    l2-normalized dict, transposed
// E     : [VOCAB][DKV]    float   @ 3 MB     (1 MB)    LN(dict) @ vq_o_w
// qn2   : [BS][64][NH]    double  @ 4 MB     (8 KB)
// kn2   : [BS][64][NH]    double  @ 4MB+8K   (8 KB)
// G     : [16][64][64]    double  @ 4MB+16K  (512 KB)
// bestp : [16][32][64][64] double @ 5 MB     (16 MB)   packed (value | v-code in low 12 bits)
// total 21 MB

// ======== fused prep: proj GEMM (blocks 0..255) + dict (blocks 256..319) ========
__global__ __launch_bounds__(256) void k_prep(
    const float* __restrict__ q_in, const float* __restrict__ k_in,
    const float* __restrict__ qpe, const float* __restrict__ kpe,
    const float* __restrict__ wi,
    const float* __restrict__ vq, const float* __restrict__ g,
    const float* __restrict__ bta, const float* __restrict__ ow,
    double* __restrict__ qp, double* __restrict__ kp,
    double* __restrict__ dnt, float* __restrict__ E)
{
    __shared__ double Sh[6528];      // proj: A-rows [2][512]; dict: Dsh + Osh
    int bid = blockIdx.x;
    int t = threadIdx.x;

    if (bid < 256) {
        // ---- proj: side(2) x b(2) x rowpair(32) x colhalf(2) ----
        int side = bid >> 7;
        int b    = (bid >> 6) & 1;
        int rp   = (bid >> 1) & 31;
        int ch   = bid & 1;
        const float* xin = side ? k_in : q_in;
        const float* pin = side ? kpe : qpe;
        double* outp = side ? kp : qp;
        int wrow0 = side ? INNER : 0;
        int r0 = rp * 2;
        for (int i = t; i < 2 * INNER; i += 256) {
            int rr = i >> 9, dd = i & 511;
            int gidx = (b * 64 + r0 + rr) * INNER + dd;
            Sh[rr * INNER + dd] = (double)xin[gidx] + (double)pin[gidx];
        }
        __syncthreads();
        int col = ch * 256 + t;
        double a0 = 0.0, a1 = 0.0;
        #pragma unroll 8
        for (int d = 0; d < INNER; ++d) {
            double w = (double)wi[(size_t)(wrow0 + d) * INNER + col];
            a0 = fma(Sh[d], w, a0);
            a1 = fma(Sh[INNER + d], w, a1);
        }
        outp[(size_t)(b * 64 + r0) * INNER + col] = a0;
        outp[(size_t)(b * 64 + r0 + 1) * INNER + col] = a1;
    } else {
        // ---- dict: 64 blocks x 64 vocab rows; wave wv does rows wv*16..wv*16+15 ----
        double* Dsh = Sh;                      // [j(64)][65] transposed dn staging
        float*  Osh = (float*)(Sh + 4160);     // ow cache 64x64 f32
        int vb = (bid - 256) * 64;
        int wv = t >> 6, lane = t & 63;
        for (int i = t; i < 4096; i += 256) Osh[i] = ow[i];
        __syncthreads();
        for (int ii = 0; ii < 16; ++ii) {
            int vloc = wv * 16 + ii;
            int v = vb + vloc;
            double z = (double)vq[v * DKV + lane];
            double s2 = z * z, s1 = z;
            for (int m = 32; m >= 1; m >>= 1) { s2 += __shfl_xor(s2, m); s1 += __shfl_xor(s1, m); }
            Dsh[lane * 65 + vloc] = z * (1.0 / sqrt(fmax(s2, 1e-12)));
            double mean = s1 * (1.0 / 64.0);
            double d0 = z - mean;
            double vv2 = d0 * d0;
            for (int m = 32; m >= 1; m >>= 1) vv2 += __shfl_xor(vv2, m);
            vv2 *= (1.0 / 64.0);
            double ln = d0 * (1.0 / sqrt(vv2 + 1e-6)) * (double)g[lane] + (double)bta[lane];
            // E[v] = LN(row) @ ow  via shfl broadcast (no wave-sync LDS round-trip)
            double acc = 0.0;
            for (int jj = 0; jj < 64; ++jj) {
                double lnj = __shfl(ln, jj);
                acc = fma(lnj, (double)Osh[jj * 64 + lane], acc);
            }
            E[v * DKV + lane] = (float)acc;
        }
        __syncthreads();
        for (int i = t; i < 4096; i += 256) {
            int j = i >> 6, vloc = i & 63;
            dnt[(size_t)j * VOCAB + vb + vloc] = Dsh[j * 65 + vloc];   // coalesced
        }
    }
}

// ======== fused sim + max-plus scan (packed-index), chunk-0 blocks also do Gram ========
__global__ __launch_bounds__(512) void k_simscan(
    const double* __restrict__ qp, const double* __restrict__ kp,
    const double* __restrict__ dnt,
    double* __restrict__ qn2, double* __restrict__ kn2,
    double* __restrict__ G, double* __restrict__ bestp)
{
    int bid = blockIdx.x;             // 512 = chunk(32) x bh(16)
    int bh = bid & 15, chunk = bid >> 4;
    int b = bh >> 3, h = bh & 7;

    __shared__ double S[16640];       // 133120 B
    double* As = S;                   // phase1: [k(64)][row(128), stride 130]
    double* Ds = S + 8320;            // phase1: [k(64)][v(128), stride 130]
    int t = threadIdx.x;

    for (int i = t; i < 8192; i += 512) {
        int row = i >> 6, kk = i & 63;       // lanes: kk consecutive -> coalesced global
        double val = (row < 64) ? qp[(size_t)(b * 64 + row) * INNER + h * 64 + kk]
                                : kp[(size_t)(b * 64 + row - 64) * INNER + h * 64 + kk];
        As[kk * 130 + row] = val;
    }
    for (int i = t; i < 8192; i += 512) {
        int kk = i >> 7, vv = i & 127;       // lanes: vv consecutive -> coalesced
        Ds[kk * 130 + vv] = dnt[(size_t)kk * VOCAB + chunk * CHUNKV + vv];
    }
    __syncthreads();

    // phase 1: sim. thread (ty 0..15 -> 8 rows, tx 0..31 -> v in {tx+32j})
    int ty = t >> 5, tx = t & 31;
    double acc[8][4];
    #pragma unroll
    for (int i = 0; i < 8; ++i)
        #pragma unroll
        for (int j = 0; j < 4; ++j) acc[i][j] = 0.0;
    for (int k = 0; k < 64; ++k) {
        double a[8], dd[4];
        #pragma unroll
        for (int i = 0; i < 8; ++i) a[i] = As[k * 130 + ty * 8 + i];   // half-wave broadcast
        #pragma unroll
        for (int j = 0; j < 4; ++j) dd[j] = Ds[k * 130 + tx + 32 * j]; // stride-8B, conflict-free
        #pragma unroll
        for (int i = 0; i < 8; ++i)
            #pragma unroll
            for (int j = 0; j < 4; ++j)
                acc[i][j] = fma(a[i], dd[j], acc[i][j]);
    }

    // chunk-0 blocks: Gram + norms from As before it's overwritten
    if (chunk == 0) {
        for (int p = t; p < 4096; p += 512) {
            int q = p >> 6, kr = p & 63;
            double s = 0.0;
            for (int d = 0; d < 64; ++d) s = fma(As[d * 130 + q], As[d * 130 + 64 + kr], s);
            G[((size_t)bh * 64 + q) * 64 + kr] = s;
        }
        if (t < 64) {
            double s = 0.0;
            for (int d = 0; d < 64; ++d) { double x = As[d * 130 + t]; s = fma(x, x, s); }
            qn2[(b * 64 + t) * NH + h] = s;
        } else if (t < 128) {
            int k2 = t - 64;
            double s = 0.0;
            for (int d = 0; d < 64; ++d) { double x = As[d * 130 + 64 + k2]; s = fma(x, x, s); }
            kn2[(b * 64 + k2) * NH + h] = s;
        }
    }
    __syncthreads();

    // write Cv[v][row]: affine to [1.25,1.75], clear low 13 bits, embed v-code on q side.
    // After q'+k' (both exp 0x3FF), the normalization right-shift puts the code
    // exactly in bits [11:0] of the stored sum; shifted-out bit is 0 -> exact.
    #pragma unroll
    for (int i = 0; i < 8; ++i) {
        int row = ty * 8 + i;
        bool isq = row < 64;
        #pragma unroll
        for (int j = 0; j < 4; ++j) {
            int vl = tx + 32 * j;
            double s = fma(acc[i][j], 1.0 / 64.0, 1.5);
            unsigned long long bb = __double_as_longlong(s) & ~0x1FFFull;
            if (isq) bb |= (unsigned long long)((4095 - (chunk * CHUNKV + vl)) << 1);
            S[vl * RS + row] = __longlong_as_double(bb);
        }
    }
    __syncthreads();

    // phase 2: scan. thread: q in {qg+16i}, k in {kg+16j}, v-half vh
    int qg = t & 15, kg = (t >> 4) & 15, vh = t >> 8;
    double best[4][4];
    #pragma unroll
    for (int i = 0; i < 4; ++i)
        #pragma unroll
        for (int j = 0; j < 4; ++j) best[i][j] = 0.0;
    int v0 = vh * 64;
    #pragma unroll 2
    for (int v = v0; v < v0 + 64; ++v) {
        double qv[4], kv[4];
        #pragma unroll
        for (int i = 0; i < 4; ++i) qv[i] = S[v * RS + qg + 16 * i];        // 16-lane contig + bcast
        #pragma unroll
        for (int j = 0; j < 4; ++j) kv[j] = S[v * RS + 64 + kg + 16 * j];   // broadcast
        #pragma unroll
        for (int i = 0; i < 4; ++i)
            #pragma unroll
            for (int j = 0; j < 4; ++j)
                best[i][j] = fmax(best[i][j], qv[i] + kv[j]);   // add_f64 + max_f64 only
    }
    __syncthreads();
    if (vh == 1) {
        #pragma unroll
        for (int i = 0; i < 4; ++i)
            #pragma unroll
            for (int j = 0; j < 4; ++j)
                S[(qg + 16 * i) * 64 + kg + 16 * j] = best[i][j];
    }
    __syncthreads();
    if (vh == 0) {
        #pragma unroll
        for (int i = 0; i < 4; ++i)
            #pragma unroll
            for (int j = 0; j < 4; ++j) {
                int q = qg + 16 * i, k = kg + 16 * j;
                double m = fmax(best[i][j], S[q * 64 + k]);
                bestp[((size_t)(bh * NCHUNK + chunk) * 64 + q) * 64 + k] = m;
            }
    }
}

// ======== combine chunk maxima, decode, wsim, epilogue ========
__global__ __launch_bounds__(256) void k_combine(
    const double* __restrict__ bestp,
    const double* __restrict__ qn2, const double* __restrict__ kn2,
    const double* __restrict__ G, const float* __restrict__ E,
    const float* __restrict__ lng, const float* __restrict__ lnb,
    float* __restrict__ out)
{
    int bid = blockIdx.x;             // 256 = bh(16) x qgroup(16)
    int bh = bid >> 4, qg = bid & 15;
    int b = bh >> 3, h = bh & 7;
    int t = threadIdx.x;
    int w = t >> 6, lane = t & 63;
    int q = qg * 4 + w;
    int k = lane;

    double best = 0.0;
    for (int c = 0; c < NCHUNK; ++c)
        best = fmax(best, bestp[((size_t)(bh * NCHUNK + c) * 64 + q) * 64 + k]);
    unsigned long long bb = __double_as_longlong(best);
    int vidx = 4095 - (int)(bb & 0xFFFull);          // code sits in bits [11:0] post-add
    double sval = __longlong_as_double(bb & ~0x1FFFull);
    double tru = (sval - 3.0) * 64.0;

    double n2 = qn2[(b * QLEN + q) * NH + h] + kn2[(b * KLEN + k) * NH + h]
              + 2.0 * G[((size_t)bh * QLEN + q) * KLEN + k];
    double wsim = tru * (1.0 / sqrt(fmax(n2, 1e-12)));

    size_t oidx = ((size_t)(b * QLEN + q) * KLEN + k) * NH + h;
    out[65536 + oidx] = (float)vidx;          // out_ids as float32
    out[131072 + oidx] = (float)wsim;         // r3_scores

    __shared__ float ws_l[4][64];
    __shared__ int  idx_l[4][64];
    ws_l[w][k] = (float)wsim;
    idx_l[w][k] = vidx;
    __syncthreads();

    int d = lane;
    float acc = 0.0f;
    for (int k2 = 0; k2 < 64; ++k2)
        acc += E[idx_l[w][k2] * DKV + d] * ws_l[w][k2];
    acc *= (1.0f / 64.0f);
    float mean = acc;
    for (int m = 32; m >= 1; m >>= 1) mean += __shfl_xor(mean, m);
    mean *= (1.0f / 64.0f);
    float dv = acc - mean;
    float var = dv * dv;
    for (int m = 32; m >= 1; m >>= 1) var += __shfl_xor(var, m);
    var *= (1.0f / 64.0f);
    float o = dv * rsqrtf(var + 1e-6f) * lng[d] + lnb[d];
    out[(((size_t)b * NH + h) * QLEN + q) * DKV + d] = o;
}

extern "C" void kernel_launch(void* const* d_in, const int* in_sizes, int n_in,
                              void* d_out, int out_size, void* d_ws, size_t ws_size,
                              hipStream_t stream) {
    const float* query = (const float*)d_in[0];
    const float* key   = (const float*)d_in[1];
    const float* qpe   = (const float*)d_in[2];
    const float* kpe   = (const float*)d_in[3];
    const float* wi    = (const float*)d_in[4];
    const float* vq    = (const float*)d_in[5];
    const float* vqg   = (const float*)d_in[6];
    const float* vqb   = (const float*)d_in[7];
    const float* ow    = (const float*)d_in[8];
    const float* lng   = (const float*)d_in[9];
    const float* lnb   = (const float*)d_in[10];
    float* out = (float*)d_out;

    char* ws = (char*)d_ws;
    double* qp  = (double*)(ws + 0);
    double* kp  = (double*)(ws + 524288);
    double* dnt = (double*)(ws + 1048576);
    float*  E   = (float*) (ws + 3145728);
    double* qn2 = (double*)(ws + 4194304);
    double* kn2 = (double*)(ws + 4202496);
    double* G   = (double*)(ws + 4210688);
    double* bestp = (double*)(ws + 5242880);

    k_prep   <<<320, 256, 0, stream>>>(query, key, qpe, kpe, wi, vq, vqg, vqb, ow,
                                       qp, kp, dnt, E);
    k_simscan<<<512, 512, 0, stream>>>(qp, kp, dnt, qn2, kn2, G, bestp);
    k_combine<<<256, 256, 0, stream>>>(bestp, qn2, kn2, G, E, lng, lnb, out);
}